// Round 1
// baseline (433.314 us; speedup 1.0000x reference)
//
#include <hip/hip_runtime.h>
#include <math.h>

#define B_    2
#define LQ_   12240
#define C_    256
#define NH_   8
#define NL_   4
#define NP_   4
#define D_    32
#define LEN_IN_ 12240
#define MROWS (B_*LQ_)   // 24480

// ---------------------------------------------------------------------------
// Tiled fp32 GEMM: C = A(MxK) @ W(KxN) + bias(N).  K % 16 == 0, N % 64 == 0.
// 64x64 block tile, 256 threads, 4x4 micro-tile per thread.
// ---------------------------------------------------------------------------
#define BM 64
#define BN 64
#define BK 16

__global__ __launch_bounds__(256) void gemm_bias_kernel(
    const float* __restrict__ A, const float* __restrict__ W,
    const float* __restrict__ bias, float* __restrict__ Cg,
    int M, int N, int K)
{
    __shared__ float As[BK][BM + 4];   // [k][m], padded
    __shared__ float Bs[BK][BN];       // [k][n]

    const int t = threadIdx.x;
    const int rowBase = blockIdx.x * BM;
    const int colBase = blockIdx.y * BN;

    const int tm = t >> 4;      // 0..15 -> output row group (4 rows)
    const int tn = t & 15;      // 0..15 -> output col group (4 cols)

    const int arow = t >> 2;    // 0..63
    const int akq  = t & 3;     // 0..3 (float4 within 16-wide K slab)

    float acc[4][4] = {};

    for (int k0 = 0; k0 < K; k0 += BK) {
        // --- stage A tile (64 rows x 16 k) ---
        float4 av = make_float4(0.f, 0.f, 0.f, 0.f);
        int grow = rowBase + arow;
        if (grow < M)
            av = *reinterpret_cast<const float4*>(A + (size_t)grow * K + k0 + akq * 4);
        As[akq * 4 + 0][arow] = av.x;
        As[akq * 4 + 1][arow] = av.y;
        As[akq * 4 + 2][arow] = av.z;
        As[akq * 4 + 3][arow] = av.w;

        // --- stage B tile (16 k x 64 cols) ---
        {
            int bk = t >> 4;            // 0..15
            int bc = (t & 15) * 4;      // 0..60
            float4 bv = *reinterpret_cast<const float4*>(
                W + (size_t)(k0 + bk) * N + colBase + bc);
            *reinterpret_cast<float4*>(&Bs[bk][bc]) = bv;
        }
        __syncthreads();

#pragma unroll
        for (int k = 0; k < BK; ++k) {
            float a[4], b[4];
            *reinterpret_cast<float4*>(a) = *reinterpret_cast<const float4*>(&As[k][tm * 4]);
            *reinterpret_cast<float4*>(b) = *reinterpret_cast<const float4*>(&Bs[k][tn * 4]);
#pragma unroll
            for (int i = 0; i < 4; ++i)
#pragma unroll
                for (int j = 0; j < 4; ++j)
                    acc[i][j] = fmaf(a[i], b[j], acc[i][j]);
        }
        __syncthreads();
    }

    // --- epilogue: bias + store ---
    float bvals[4];
#pragma unroll
    for (int j = 0; j < 4; ++j) bvals[j] = bias[colBase + tn * 4 + j];

#pragma unroll
    for (int i = 0; i < 4; ++i) {
        int r = rowBase + tm * 4 + i;
        if (r < M) {
            float4 o;
            o.x = acc[i][0] + bvals[0];
            o.y = acc[i][1] + bvals[1];
            o.z = acc[i][2] + bvals[2];
            o.w = acc[i][3] + bvals[3];
            *reinterpret_cast<float4*>(Cg + (size_t)r * N + colBase + tn * 4) = o;
        }
    }
}

// ---------------------------------------------------------------------------
// Fused softmax + bilinear sampling.  One block (256 thr) per (b,q).
// Thread t -> head h = t>>5, dim d = t&31 (coalesced 128B gathers per head).
// ---------------------------------------------------------------------------
__global__ __launch_bounds__(256) void sampler_kernel(
    const float* __restrict__ value,   // (B, LEN_IN, 256)
    const float* __restrict__ offs,    // (B*LQ, 256)
    const float* __restrict__ attnw,   // (B*LQ, 128)
    const float* __restrict__ refp,    // (B, LQ, NL, 2)
    const int*   __restrict__ shapes,  // (NL, 2)  [H, W]
    const int*   __restrict__ starts,  // (NL,)
    float* __restrict__ mid)           // (B*LQ, 256)
{
    const int bq = blockIdx.x;
    const int b  = bq / LQ_;
    const int t  = threadIdx.x;

    __shared__ float s_off[256];
    __shared__ float s_attn[128];
    __shared__ float s_ref[NL_ * 2];
    __shared__ int   s_shape[NL_ * 2];
    __shared__ int   s_start[NL_];

    s_off[t] = offs[(size_t)bq * 256 + t];
    if (t < 128) s_attn[t] = attnw[(size_t)bq * 128 + t];
    if (t < NL_ * 2) {
        s_ref[t]   = refp[(size_t)bq * (NL_ * 2) + t];
        s_shape[t] = shapes[t];
    }
    if (t < NL_) s_start[t] = starts[t];
    __syncthreads();

    // per-head softmax over NL*NP = 16 entries (8 serial threads, short)
    if (t < NH_) {
        float mx = -1e30f;
        for (int i = 0; i < 16; ++i) mx = fmaxf(mx, s_attn[t * 16 + i]);
        float sum = 0.f;
        for (int i = 0; i < 16; ++i) {
            float e = expf(s_attn[t * 16 + i] - mx);
            s_attn[t * 16 + i] = e;
            sum += e;
        }
        float r = 1.f / sum;
        for (int i = 0; i < 16; ++i) s_attn[t * 16 + i] *= r;
    }
    __syncthreads();

    const int h = t >> 5;
    const int d = t & 31;
    const float* vbase = value + (size_t)b * LEN_IN_ * 256;

    float acc = 0.f;
#pragma unroll
    for (int l = 0; l < NL_; ++l) {
        const int Hl = s_shape[l * 2 + 0];
        const int Wl = s_shape[l * 2 + 1];
        const int s  = s_start[l];
        const float rx = s_ref[l * 2 + 0];
        const float ry = s_ref[l * 2 + 1];
        const float fW = (float)Wl, fH = (float)Hl;
#pragma unroll
        for (int p = 0; p < NP_; ++p) {
            const int c = ((h * NL_ + l) * NP_ + p) * 2;
            const float ox = s_off[c + 0];
            const float oy = s_off[c + 1];
            const float locx = rx + ox / fW;
            const float locy = ry + oy / fH;
            const float x = locx * fW - 0.5f;
            const float y = locy * fH - 0.5f;
            const float x0f = floorf(x), y0f = floorf(y);
            const float fx = x - x0f, fy = y - y0f;
            const int x0 = (int)x0f, y0 = (int)y0f;
            const float w = s_attn[h * 16 + l * 4 + p];

            float v00 = 0.f, v01 = 0.f, v10 = 0.f, v11 = 0.f;
            const int x1 = x0 + 1, y1 = y0 + 1;
            const bool xv0 = (x0 >= 0) & (x0 < Wl);
            const bool xv1 = (x1 >= 0) & (x1 < Wl);
            const bool yv0 = (y0 >= 0) & (y0 < Hl);
            const bool yv1 = (y1 >= 0) & (y1 < Hl);
            const int col = h * 32 + d;
            if (yv0) {
                const size_t rowb = (size_t)(s + y0 * Wl) * 256;
                if (xv0) v00 = vbase[rowb + (size_t)x0 * 256 + col];
                if (xv1) v01 = vbase[rowb + (size_t)x1 * 256 + col];
            }
            if (yv1) {
                const size_t rowb = (size_t)(s + y1 * Wl) * 256;
                if (xv0) v10 = vbase[rowb + (size_t)x0 * 256 + col];
                if (xv1) v11 = vbase[rowb + (size_t)x1 * 256 + col];
            }
            const float sample = v00 * (1.f - fx) * (1.f - fy)
                               + v01 * fx * (1.f - fy)
                               + v10 * (1.f - fx) * fy
                               + v11 * fx * fy;
            acc = fmaf(w, sample, acc);
        }
    }
    mid[(size_t)bq * 256 + t] = acc;
}

// ---------------------------------------------------------------------------
extern "C" void kernel_launch(void* const* d_in, const int* in_sizes, int n_in,
                              void* d_out, int out_size, void* d_ws, size_t ws_size,
                              hipStream_t stream)
{
    const float* query  = (const float*)d_in[0];
    const float* refp   = (const float*)d_in[1];
    const float* inflat = (const float*)d_in[2];
    const int*   shapes = (const int*)d_in[3];
    const int*   starts = (const int*)d_in[4];
    const float* W_off  = (const float*)d_in[5];
    const float* b_off  = (const float*)d_in[6];
    const float* W_attn = (const float*)d_in[7];
    const float* b_attn = (const float*)d_in[8];
    const float* W_val  = (const float*)d_in[9];
    const float* b_val  = (const float*)d_in[10];
    const float* W_out  = (const float*)d_in[11];
    const float* b_out  = (const float*)d_in[12];
    float* out = (float*)d_out;

    float* value = (float*)d_ws;                       // 24480*256
    float* offsb = value + (size_t)MROWS * C_;         // 24480*256
    float* attnb = offsb + (size_t)MROWS * C_;         // 24480*128
    float* mid   = attnb + (size_t)MROWS * 128;        // 24480*256

    dim3 blk(256);
    dim3 g1((MROWS + BM - 1) / BM, C_ / BN);
    dim3 g2((MROWS + BM - 1) / BM, 128 / BN);

    hipLaunchKernelGGL(gemm_bias_kernel, g1, blk, 0, stream,
                       inflat, W_val, b_val, value, MROWS, C_, C_);
    hipLaunchKernelGGL(gemm_bias_kernel, g1, blk, 0, stream,
                       query, W_off, b_off, offsb, MROWS, C_, C_);
    hipLaunchKernelGGL(gemm_bias_kernel, g2, blk, 0, stream,
                       query, W_attn, b_attn, attnb, MROWS, 128, C_);
    hipLaunchKernelGGL(sampler_kernel, dim3(MROWS), blk, 0, stream,
                       value, offsb, attnb, refp, shapes, starts, mid);
    hipLaunchKernelGGL(gemm_bias_kernel, g1, blk, 0, stream,
                       mid, W_out, b_out, out, MROWS, C_, C_);
}

// Round 2
// 267.979 us; speedup vs baseline: 1.6170x; 1.6170x over previous
//
#include <hip/hip_runtime.h>
#include <math.h>

#define B_    2
#define LQ_   12240
#define C_    256
#define NH_   8
#define NL_   4
#define NP_   4
#define D_    32
#define LEN_IN_ 12240
#define MROWS (B_*LQ_)   // 24480

// ---------------------------------------------------------------------------
// Tiled fp32 GEMM: C = A(MxK) @ W(KxN) + bias(N).  K % 16 == 0, N % 64 == 0.
// ---------------------------------------------------------------------------
#define BM 64
#define BN 64
#define BK 16

__global__ __launch_bounds__(256) void gemm_bias_kernel(
    const float* __restrict__ A, const float* __restrict__ W,
    const float* __restrict__ bias, float* __restrict__ Cg,
    int M, int N, int K)
{
    __shared__ float As[BK][BM + 4];
    __shared__ float Bs[BK][BN];

    const int t = threadIdx.x;
    const int rowBase = blockIdx.x * BM;
    const int colBase = blockIdx.y * BN;

    const int tm = t >> 4;
    const int tn = t & 15;
    const int arow = t >> 2;
    const int akq  = t & 3;

    float acc[4][4] = {};

    for (int k0 = 0; k0 < K; k0 += BK) {
        float4 av = make_float4(0.f, 0.f, 0.f, 0.f);
        int grow = rowBase + arow;
        if (grow < M)
            av = *reinterpret_cast<const float4*>(A + (size_t)grow * K + k0 + akq * 4);
        As[akq * 4 + 0][arow] = av.x;
        As[akq * 4 + 1][arow] = av.y;
        As[akq * 4 + 2][arow] = av.z;
        As[akq * 4 + 3][arow] = av.w;
        {
            int bk = t >> 4;
            int bc = (t & 15) * 4;
            float4 bv = *reinterpret_cast<const float4*>(
                W + (size_t)(k0 + bk) * N + colBase + bc);
            *reinterpret_cast<float4*>(&Bs[bk][bc]) = bv;
        }
        __syncthreads();

#pragma unroll
        for (int k = 0; k < BK; ++k) {
            float a[4], b[4];
            *reinterpret_cast<float4*>(a) = *reinterpret_cast<const float4*>(&As[k][tm * 4]);
            *reinterpret_cast<float4*>(b) = *reinterpret_cast<const float4*>(&Bs[k][tn * 4]);
#pragma unroll
            for (int i = 0; i < 4; ++i)
#pragma unroll
                for (int j = 0; j < 4; ++j)
                    acc[i][j] = fmaf(a[i], b[j], acc[i][j]);
        }
        __syncthreads();
    }

    float bvals[4];
#pragma unroll
    for (int j = 0; j < 4; ++j) bvals[j] = bias[colBase + tn * 4 + j];

#pragma unroll
    for (int i = 0; i < 4; ++i) {
        int r = rowBase + tm * 4 + i;
        if (r < M) {
            float4 o;
            o.x = acc[i][0] + bvals[0];
            o.y = acc[i][1] + bvals[1];
            o.z = acc[i][2] + bvals[2];
            o.w = acc[i][3] + bvals[3];
            *reinterpret_cast<float4*>(Cg + (size_t)r * N + colBase + tn * 4) = o;
        }
    }
}

// ---------------------------------------------------------------------------
// Fused softmax + bilinear sampling, restructured:
//   block = 128 threads, one (b,q) per block.
//   PREP: thread t = h*16 + (l*4+p) owns one sampling point: softmax via
//         16-wide shfl, address algebra with static level geometry
//         (W=96>>l, start=12288-(12288>>2l)), clamped addrs + masked weights
//         -> LDS (int4 addr, float4 weight), layout [pt][h] (read-conflict-free).
//   MAIN: thread t = h*16 + d2 gathers float2; 4 loads + 8 FMA per point.
// ---------------------------------------------------------------------------
__global__ __launch_bounds__(128) void sampler_kernel(
    const float* __restrict__ value,   // (B, LEN_IN, 256)
    const float* __restrict__ offs,    // (B*LQ, 256)
    const float* __restrict__ attnw,   // (B*LQ, 128)
    const float* __restrict__ refp,    // (B, LQ, NL, 2)
    float* __restrict__ mid)           // (B*LQ, 256)
{
    const int bq = blockIdx.x;
    const int t  = threadIdx.x;

    __shared__ float s_ref[NL_ * 2];
    __shared__ int   s_addr[128 * 4];
    __shared__ float s_w[128 * 4];

    if (t < NL_ * 2) s_ref[t] = refp[(size_t)bq * (NL_ * 2) + t];
    __syncthreads();

    // ---- PREP: one point per thread ----
    {
        const int h  = t >> 4;
        const int lp = t & 15;
        const int l  = lp >> 2;

        // softmax over the 16 (l,p) entries of this head, via shfl within
        // the 16-lane subgroup (lanes of one h are contiguous).
        float raw = attnw[(size_t)bq * 128 + t];
        float mx = raw;
#pragma unroll
        for (int m = 8; m >= 1; m >>= 1) mx = fmaxf(mx, __shfl_xor(mx, m, 16));
        float e = __expf(raw - mx);
        float sum = e;
#pragma unroll
        for (int m = 8; m >= 1; m >>= 1) sum += __shfl_xor(sum, m, 16);
        const float aw = e / sum;

        const float2 o = reinterpret_cast<const float2*>(offs)[(size_t)bq * 128 + t];
        const float rx = s_ref[l * 2 + 0];
        const float ry = s_ref[l * 2 + 1];

        const int   Wl = 96 >> l;           // H == W per level
        const int   st = 12288 - (12288 >> (2 * l));
        const float fW = (float)Wl;

        const float x = fmaf(rx, fW, o.x) - 0.5f;
        const float y = fmaf(ry, fW, o.y) - 0.5f;
        const float x0f = floorf(x), y0f = floorf(y);
        const float fx = x - x0f, fy = y - y0f;
        const int x0 = (int)x0f, y0 = (int)y0f;
        const int x1 = x0 + 1,   y1 = y0 + 1;

        const float vx0 = (x0 >= 0 && x0 < Wl) ? 1.f : 0.f;
        const float vx1 = (x1 >= 0 && x1 < Wl) ? 1.f : 0.f;
        const float vy0 = (y0 >= 0 && y0 < Wl) ? 1.f : 0.f;
        const float vy1 = (y1 >= 0 && y1 < Wl) ? 1.f : 0.f;

        const int xc0 = min(max(x0, 0), Wl - 1);
        const int xc1 = min(max(x1, 0), Wl - 1);
        const int yc0 = min(max(y0, 0), Wl - 1);
        const int yc1 = min(max(y1, 0), Wl - 1);

        const int row0 = st + yc0 * Wl;
        const int row1 = st + yc1 * Wl;
        const int hb   = h << 5;

        const int sidx = (lp * 8 + h) * 4;   // [pt][h] layout
        int4 a;
        a.x = ((row0 + xc0) << 8) + hb;
        a.y = ((row0 + xc1) << 8) + hb;
        a.z = ((row1 + xc0) << 8) + hb;
        a.w = ((row1 + xc1) << 8) + hb;
        *reinterpret_cast<int4*>(&s_addr[sidx]) = a;

        float4 w;
        w.x = aw * (1.f - fx) * (1.f - fy) * vx0 * vy0;
        w.y = aw * fx * (1.f - fy) * vx1 * vy0;
        w.z = aw * (1.f - fx) * fy * vx0 * vy1;
        w.w = aw * fx * fy * vx1 * vy1;
        *reinterpret_cast<float4*>(&s_w[sidx]) = w;
    }
    __syncthreads();

    // ---- MAIN: gather + weighted sum ----
    const int h  = t >> 4;
    const int d2 = (t & 15) * 2;
    const float* __restrict__ vb = value + (bq >= LQ_ ? (size_t)LQ_ * LEN_IN_ * 0 + (size_t)LEN_IN_ * 256 : 0);

    float accx = 0.f, accy = 0.f;
#pragma unroll
    for (int pt = 0; pt < 16; ++pt) {
        const int sidx = (pt * 8 + h) * 4;
        const int4   a = *reinterpret_cast<const int4*>(&s_addr[sidx]);
        const float4 w = *reinterpret_cast<const float4*>(&s_w[sidx]);
        const float2 v00 = *reinterpret_cast<const float2*>(vb + a.x + d2);
        const float2 v01 = *reinterpret_cast<const float2*>(vb + a.y + d2);
        const float2 v10 = *reinterpret_cast<const float2*>(vb + a.z + d2);
        const float2 v11 = *reinterpret_cast<const float2*>(vb + a.w + d2);
        accx = fmaf(w.x, v00.x, accx); accy = fmaf(w.x, v00.y, accy);
        accx = fmaf(w.y, v01.x, accx); accy = fmaf(w.y, v01.y, accy);
        accx = fmaf(w.z, v10.x, accx); accy = fmaf(w.z, v10.y, accy);
        accx = fmaf(w.w, v11.x, accx); accy = fmaf(w.w, v11.y, accy);
    }

    float2 o2; o2.x = accx; o2.y = accy;
    *reinterpret_cast<float2*>(mid + (size_t)bq * 256 + (h << 5) + d2) = o2;
}

// ---------------------------------------------------------------------------
extern "C" void kernel_launch(void* const* d_in, const int* in_sizes, int n_in,
                              void* d_out, int out_size, void* d_ws, size_t ws_size,
                              hipStream_t stream)
{
    const float* query  = (const float*)d_in[0];
    const float* refp   = (const float*)d_in[1];
    const float* inflat = (const float*)d_in[2];
    const float* W_off  = (const float*)d_in[5];
    const float* b_off  = (const float*)d_in[6];
    const float* W_attn = (const float*)d_in[7];
    const float* b_attn = (const float*)d_in[8];
    const float* W_val  = (const float*)d_in[9];
    const float* b_val  = (const float*)d_in[10];
    const float* W_out  = (const float*)d_in[11];
    const float* b_out  = (const float*)d_in[12];
    float* out = (float*)d_out;

    float* value = (float*)d_ws;
    float* offsb = value + (size_t)MROWS * C_;
    float* attnb = offsb + (size_t)MROWS * C_;
    float* mid   = attnb + (size_t)MROWS * 128;

    dim3 blk(256);
    dim3 g1((MROWS + BM - 1) / BM, C_ / BN);
    dim3 g2((MROWS + BM - 1) / BM, 128 / BN);

    hipLaunchKernelGGL(gemm_bias_kernel, g1, blk, 0, stream,
                       inflat, W_val, b_val, value, MROWS, C_, C_);
    hipLaunchKernelGGL(gemm_bias_kernel, g1, blk, 0, stream,
                       query, W_off, b_off, offsb, MROWS, C_, C_);
    hipLaunchKernelGGL(gemm_bias_kernel, g2, blk, 0, stream,
                       query, W_attn, b_attn, attnb, MROWS, 128, C_);
    hipLaunchKernelGGL(sampler_kernel, dim3(MROWS), dim3(128), 0, stream,
                       value, offsb, attnb, refp, mid);
    hipLaunchKernelGGL(gemm_bias_kernel, g1, blk, 0, stream,
                       mid, W_out, b_out, out, MROWS, C_, C_);
}

// Round 3
// 198.029 us; speedup vs baseline: 2.1881x; 1.3532x over previous
//
#include <hip/hip_runtime.h>
#include <math.h>

#define B_    2
#define LQ_   12240
#define C_    256
#define NH_   8
#define NL_   4
#define NP_   4
#define LEN_IN_ 12240
#define MROWS (B_*LQ_)   // 24480

typedef __attribute__((ext_vector_type(8))) short short8v;   // 8 bf16
typedef __attribute__((ext_vector_type(4))) float f32x4;

__device__ __forceinline__ ushort f2bf_hi(float f) {
    uint u = __builtin_bit_cast(uint, f);
    uint r = (u + 0x7fffu + ((u >> 16) & 1u)) >> 16;
    return (ushort)r;
}
__device__ __forceinline__ float bf2f(ushort h) {
    uint u = ((uint)h) << 16;
    return __builtin_bit_cast(float, u);
}

// packed-B region layout (ushort elements)
#define OFF_VHI 0
#define OFF_VLO 65536
#define OFF_OHI 131072
#define OFF_OLO 196608
#define OFF_AHI 262144
#define OFF_ALO 294912
#define OFF_UHI 327680
#define OFF_ULO 393216
#define PACK_TOTAL 458752

// ---------------------------------------------------------------------------
// Pack all 4 weight matrices into MFMA B-fragment order, split hi/lo bf16.
// B-frag (16x16x32): lane l holds B[k = kf*32 + (l>>4)*8 + j][col = nf*16 + (l&15)]
// packed index: (((nf*KF)+kf)*64 + l)*8 + j    (KF = 8 for K=256)
// gid ranges: [0,8192) W_val | [8192,16384) W_off | [16384,20480) W_attn(N=128)
//             [20480,28672) W_out
// ---------------------------------------------------------------------------
__global__ __launch_bounds__(256) void pack_b_kernel(
    const float* __restrict__ Wv, const float* __restrict__ Wo,
    const float* __restrict__ Wa, const float* __restrict__ Wu,
    ushort* __restrict__ out)
{
    int gid = blockIdx.x * 256 + threadIdx.x;
    const float* W; ushort* hi; ushort* lo; int N, rel;
    if (gid < 8192)       { W = Wv; hi = out + OFF_VHI; lo = out + OFF_VLO; N = 256; rel = gid; }
    else if (gid < 16384) { W = Wo; hi = out + OFF_OHI; lo = out + OFF_OLO; N = 256; rel = gid - 8192; }
    else if (gid < 20480) { W = Wa; hi = out + OFF_AHI; lo = out + OFF_ALO; N = 128; rel = gid - 16384; }
    else if (gid < 28672) { W = Wu; hi = out + OFF_UHI; lo = out + OFF_ULO; N = 256; rel = gid - 20480; }
    else return;

    const int lane = rel & 63;
    const int kf   = (rel >> 6) & 7;     // KF = 8
    const int nf   = rel >> 9;
    const int row0 = kf * 32 + (lane >> 4) * 8;
    const int col  = nf * 16 + (lane & 15);

    ushort h8[8], l8[8];
#pragma unroll
    for (int j = 0; j < 8; ++j) {
        float x = W[(size_t)(row0 + j) * N + col];
        ushort h = f2bf_hi(x);
        h8[j] = h;
        l8[j] = f2bf_hi(x - bf2f(h));
    }
    union { ushort u16[8]; uint4 u4; } ch, cl;
#pragma unroll
    for (int j = 0; j < 8; ++j) { ch.u16[j] = h8[j]; cl.u16[j] = l8[j]; }
    *reinterpret_cast<uint4*>(hi + (size_t)rel * 8) = ch.u4;
    *reinterpret_cast<uint4*>(lo + (size_t)rel * 8) = cl.u4;
}

// ---------------------------------------------------------------------------
// Split-bf16 MFMA GEMM: C = A(MxK,fp32) @ W(KxN) + bias, K=256.
// BM=128, BN=64, BK=32, 256 thr (4 waves), wave tile 32x64 (2x4 16x16 frags).
// NPASS=3: acc += Ahi*Bhi + Ahi*Blo + Alo*Bhi   (~2^-16 rel err)
// NPASS=1: acc += Ahi*Bhi                        (~2^-8 rel err)
// A reg-staged fp32 -> split bf16 in LDS; B read pre-packed from global (L2).
// ---------------------------------------------------------------------------
template<int NPASS>
__global__ __launch_bounds__(256) void gemm_mfma_kernel(
    const float* __restrict__ A, const ushort* __restrict__ Bhi,
    const ushort* __restrict__ Blo, const float* __restrict__ bias,
    float* __restrict__ Cg, int M, int N, int K)
{
    const int t = threadIdx.x, lane = t & 63, wid = t >> 6;
    const int rowBase = blockIdx.x * 128;
    const int colBase = blockIdx.y * 64;
    const int KF = K >> 5;

    __shared__ ushort Ah[128][40];   // +8 pad: bank-spread for frag reads
    __shared__ ushort Al[128][40];

    f32x4 acc[2][4];
#pragma unroll
    for (int i = 0; i < 2; ++i)
#pragma unroll
        for (int j = 0; j < 4; ++j) acc[i][j] = (f32x4)0.0f;

    const int waveRow = wid * 32;
    const int frRow = lane & 15, chunk = lane >> 4;

    for (int kf = 0; kf < KF; ++kf) {
        // ---- stage A tile (128 x 32) fp32 -> bf16 hi/lo ----
#pragma unroll
        for (int i = 0; i < 4; ++i) {
            int idx = i * 256 + t;
            int r = idx >> 3, c4 = (idx & 7) * 4;
            int grow = rowBase + r;
            float4 v = make_float4(0.f, 0.f, 0.f, 0.f);
            if (grow < M)
                v = *reinterpret_cast<const float4*>(A + (size_t)grow * K + kf * 32 + c4);
            ushort h0 = f2bf_hi(v.x), h1 = f2bf_hi(v.y), h2 = f2bf_hi(v.z), h3 = f2bf_hi(v.w);
            *reinterpret_cast<ushort4*>(&Ah[r][c4]) = make_ushort4(h0, h1, h2, h3);
            if (NPASS == 3) {
                ushort l0 = f2bf_hi(v.x - bf2f(h0)), l1 = f2bf_hi(v.y - bf2f(h1));
                ushort l2 = f2bf_hi(v.z - bf2f(h2)), l3 = f2bf_hi(v.w - bf2f(h3));
                *reinterpret_cast<ushort4*>(&Al[r][c4]) = make_ushort4(l0, l1, l2, l3);
            }
        }
        __syncthreads();

        // ---- B fragments from packed global (L2-resident) ----
        uint4 bh[4], bl[4];
#pragma unroll
        for (int f = 0; f < 4; ++f) {
            size_t bidx = ((size_t)((colBase >> 4) + f) * KF + kf) * 64 + lane;
            bh[f] = reinterpret_cast<const uint4*>(Bhi)[bidx];
            if (NPASS == 3) bl[f] = reinterpret_cast<const uint4*>(Blo)[bidx];
        }
        // ---- A fragments from LDS ----
        uint4 ah[2], al[2];
#pragma unroll
        for (int rf = 0; rf < 2; ++rf) {
            int row = waveRow + rf * 16 + frRow;
            ah[rf] = *reinterpret_cast<const uint4*>(&Ah[row][chunk * 8]);
            if (NPASS == 3) al[rf] = *reinterpret_cast<const uint4*>(&Al[row][chunk * 8]);
        }
        // ---- MFMA ----
#pragma unroll
        for (int rf = 0; rf < 2; ++rf)
#pragma unroll
            for (int f = 0; f < 4; ++f) {
                short8v a = __builtin_bit_cast(short8v, ah[rf]);
                short8v b = __builtin_bit_cast(short8v, bh[f]);
                acc[rf][f] = __builtin_amdgcn_mfma_f32_16x16x32_bf16(a, b, acc[rf][f], 0, 0, 0);
                if (NPASS == 3) {
                    acc[rf][f] = __builtin_amdgcn_mfma_f32_16x16x32_bf16(
                        a, __builtin_bit_cast(short8v, bl[f]), acc[rf][f], 0, 0, 0);
                    acc[rf][f] = __builtin_amdgcn_mfma_f32_16x16x32_bf16(
                        __builtin_bit_cast(short8v, al[rf]), b, acc[rf][f], 0, 0, 0);
                }
            }
        __syncthreads();
    }

    // ---- epilogue: bias + store (C/D: col = lane&15, row = (lane>>4)*4+e) ----
    const int colLane = lane & 15, rquad = lane >> 4;
#pragma unroll
    for (int f = 0; f < 4; ++f) {
        int col = colBase + f * 16 + colLane;
        float bv = bias[col];
#pragma unroll
        for (int rf = 0; rf < 2; ++rf)
#pragma unroll
            for (int e = 0; e < 4; ++e) {
                int row = rowBase + waveRow + rf * 16 + rquad * 4 + e;
                if (row < M) Cg[(size_t)row * N + col] = acc[rf][f][e] + bv;
            }
    }
}

// ---------------------------------------------------------------------------
// Fused softmax + bilinear sampling (R1 structure, padded LDS stride 9).
// ---------------------------------------------------------------------------
__global__ __launch_bounds__(128) void sampler_kernel(
    const float* __restrict__ value,   // (B, LEN_IN, 256)
    const float* __restrict__ offs,    // (B*LQ, 256)
    const float* __restrict__ attnw,   // (B*LQ, 128)
    const float* __restrict__ refp,    // (B, LQ, NL, 2)
    float* __restrict__ mid)           // (B*LQ, 256)
{
    const int bq = blockIdx.x;
    const int t  = threadIdx.x;

    __shared__ float s_ref[NL_ * 2];
    __shared__ int   s_addr[144 * 4];
    __shared__ float s_w[144 * 4];

    if (t < NL_ * 2) s_ref[t] = refp[(size_t)bq * (NL_ * 2) + t];
    __syncthreads();

    {
        const int h  = t >> 4;
        const int lp = t & 15;
        const int l  = lp >> 2;

        float raw = attnw[(size_t)bq * 128 + t];
        float mx = raw;
#pragma unroll
        for (int m = 8; m >= 1; m >>= 1) mx = fmaxf(mx, __shfl_xor(mx, m, 16));
        float e = __expf(raw - mx);
        float sum = e;
#pragma unroll
        for (int m = 8; m >= 1; m >>= 1) sum += __shfl_xor(sum, m, 16);
        const float aw = e / sum;

        const float2 o = reinterpret_cast<const float2*>(offs)[(size_t)bq * 128 + t];
        const float rx = s_ref[l * 2 + 0];
        const float ry = s_ref[l * 2 + 1];

        const int   Wl = 96 >> l;
        const int   st = 12288 - (12288 >> (2 * l));
        const float fW = (float)Wl;

        const float x = fmaf(rx, fW, o.x) - 0.5f;
        const float y = fmaf(ry, fW, o.y) - 0.5f;
        const float x0f = floorf(x), y0f = floorf(y);
        const float fx = x - x0f, fy = y - y0f;
        const int x0 = (int)x0f, y0 = (int)y0f;
        const int x1 = x0 + 1,   y1 = y0 + 1;

        const float vx0 = (x0 >= 0 && x0 < Wl) ? 1.f : 0.f;
        const float vx1 = (x1 >= 0 && x1 < Wl) ? 1.f : 0.f;
        const float vy0 = (y0 >= 0 && y0 < Wl) ? 1.f : 0.f;
        const float vy1 = (y1 >= 0 && y1 < Wl) ? 1.f : 0.f;

        const int xc0 = min(max(x0, 0), Wl - 1);
        const int xc1 = min(max(x1, 0), Wl - 1);
        const int yc0 = min(max(y0, 0), Wl - 1);
        const int yc1 = min(max(y1, 0), Wl - 1);

        const int row0 = st + yc0 * Wl;
        const int row1 = st + yc1 * Wl;
        const int hb   = h << 5;

        const int sidx = (lp * 9 + h) * 4;   // padded stride 9 -> conflict-free
        int4 a;
        a.x = ((row0 + xc0) << 8) + hb;
        a.y = ((row0 + xc1) << 8) + hb;
        a.z = ((row1 + xc0) << 8) + hb;
        a.w = ((row1 + xc1) << 8) + hb;
        *reinterpret_cast<int4*>(&s_addr[sidx]) = a;

        float4 w;
        w.x = aw * (1.f - fx) * (1.f - fy) * vx0 * vy0;
        w.y = aw * fx * (1.f - fy) * vx1 * vy0;
        w.z = aw * (1.f - fx) * fy * vx0 * vy1;
        w.w = aw * fx * fy * vx1 * vy1;
        *reinterpret_cast<float4*>(&s_w[sidx]) = w;
    }
    __syncthreads();

    const int h  = t >> 4;
    const int d2 = (t & 15) * 2;
    const float* __restrict__ vb = value + (bq >= LQ_ ? (size_t)LEN_IN_ * 256 : 0);

    float accx = 0.f, accy = 0.f;
#pragma unroll
    for (int pt = 0; pt < 16; ++pt) {
        const int sidx = (pt * 9 + h) * 4;
        const int4   a = *reinterpret_cast<const int4*>(&s_addr[sidx]);
        const float4 w = *reinterpret_cast<const float4*>(&s_w[sidx]);
        const float2 v00 = *reinterpret_cast<const float2*>(vb + a.x + d2);
        const float2 v01 = *reinterpret_cast<const float2*>(vb + a.y + d2);
        const float2 v10 = *reinterpret_cast<const float2*>(vb + a.z + d2);
        const float2 v11 = *reinterpret_cast<const float2*>(vb + a.w + d2);
        accx = fmaf(w.x, v00.x, accx); accy = fmaf(w.x, v00.y, accy);
        accx = fmaf(w.y, v01.x, accx); accy = fmaf(w.y, v01.y, accy);
        accx = fmaf(w.z, v10.x, accx); accy = fmaf(w.z, v10.y, accy);
        accx = fmaf(w.w, v11.x, accx); accy = fmaf(w.w, v11.y, accy);
    }

    float2 o2; o2.x = accx; o2.y = accy;
    *reinterpret_cast<float2*>(mid + (size_t)bq * 256 + (h << 5) + d2) = o2;
}

// ---------------------------------------------------------------------------
extern "C" void kernel_launch(void* const* d_in, const int* in_sizes, int n_in,
                              void* d_out, int out_size, void* d_ws, size_t ws_size,
                              hipStream_t stream)
{
    const float* query  = (const float*)d_in[0];
    const float* refp   = (const float*)d_in[1];
    const float* inflat = (const float*)d_in[2];
    const float* W_off  = (const float*)d_in[5];
    const float* b_off  = (const float*)d_in[6];
    const float* W_attn = (const float*)d_in[7];
    const float* b_attn = (const float*)d_in[8];
    const float* W_val  = (const float*)d_in[9];
    const float* b_val  = (const float*)d_in[10];
    const float* W_out  = (const float*)d_in[11];
    const float* b_out  = (const float*)d_in[12];
    float* out = (float*)d_out;

    float* value = (float*)d_ws;                       // 24480*256
    float* offsb = value + (size_t)MROWS * C_;         // 24480*256
    float* attnb = offsb + (size_t)MROWS * C_;         // 24480*128
    float* mid   = attnb + (size_t)MROWS * 128;        // 24480*256
    ushort* pack = (ushort*)(mid + (size_t)MROWS * C_);

    dim3 blk(256);

    hipLaunchKernelGGL(pack_b_kernel, dim3(112), blk, 0, stream,
                       W_val, W_off, W_attn, W_out, pack);
    hipLaunchKernelGGL((gemm_mfma_kernel<3>), dim3(192, 4), blk, 0, stream,
                       inflat, pack + OFF_VHI, pack + OFF_VLO, b_val, value, MROWS, C_, C_);
    hipLaunchKernelGGL((gemm_mfma_kernel<1>), dim3(192, 4), blk, 0, stream,
                       query, pack + OFF_OHI, pack + OFF_OLO, b_off, offsb, MROWS, C_, C_);
    hipLaunchKernelGGL((gemm_mfma_kernel<1>), dim3(192, 2), blk, 0, stream,
                       query, pack + OFF_AHI, pack + OFF_ALO, b_attn, attnb, MROWS, 128, C_);
    hipLaunchKernelGGL(sampler_kernel, dim3(MROWS), dim3(128), 0, stream,
                       value, offsb, attnb, refp, mid);
    hipLaunchKernelGGL((gemm_mfma_kernel<3>), dim3(192, 4), blk, 0, stream,
                       mid, pack + OFF_UHI, pack + OFF_ULO, b_out, out, MROWS, C_, C_);
}

// Round 4
// 159.700 us; speedup vs baseline: 2.7133x; 1.2400x over previous
//
#include <hip/hip_runtime.h>
#include <math.h>

#define B_    2
#define LQ_   12240
#define C_    256
#define NH_   8
#define NL_   4
#define NP_   4
#define LEN_IN_ 12240
#define MROWS (B_*LQ_)   // 24480

typedef __attribute__((ext_vector_type(8))) short short8v;   // 8 bf16
typedef __attribute__((ext_vector_type(4))) float f32x4;

__device__ __forceinline__ ushort f2bf_hi(float f) {
    uint u = __builtin_bit_cast(uint, f);
    uint r = (u + 0x7fffu + ((u >> 16) & 1u)) >> 16;
    return (ushort)r;
}
__device__ __forceinline__ float bf2f(ushort h) {
    uint u = ((uint)h) << 16;
    return __builtin_bit_cast(float, u);
}

// packed-B region layout (ushort elements)
#define OFF_VHI 0
#define OFF_VLO 65536
#define OFF_OHI 131072
#define OFF_OLO 196608
#define OFF_AHI 262144
#define OFF_ALO 294912
#define OFF_UHI 327680
#define OFF_ULO 393216
#define PACK_TOTAL 458752

// ---------------------------------------------------------------------------
// Pack weight matrices into MFMA B-fragment order, split hi/lo bf16.
// packed index: (((nf*KF)+kf)*64 + lane)*8 + j   (KF = 8 for K=256)
// ---------------------------------------------------------------------------
__global__ __launch_bounds__(256) void pack_b_kernel(
    const float* __restrict__ Wv, const float* __restrict__ Wo,
    const float* __restrict__ Wa, const float* __restrict__ Wu,
    ushort* __restrict__ out)
{
    int gid = blockIdx.x * 256 + threadIdx.x;
    const float* W; ushort* hi; ushort* lo; int N, rel;
    if (gid < 8192)       { W = Wv; hi = out + OFF_VHI; lo = out + OFF_VLO; N = 256; rel = gid; }
    else if (gid < 16384) { W = Wo; hi = out + OFF_OHI; lo = out + OFF_OLO; N = 256; rel = gid - 8192; }
    else if (gid < 20480) { W = Wa; hi = out + OFF_AHI; lo = out + OFF_ALO; N = 128; rel = gid - 16384; }
    else if (gid < 28672) { W = Wu; hi = out + OFF_UHI; lo = out + OFF_ULO; N = 256; rel = gid - 20480; }
    else return;

    const int lane = rel & 63;
    const int kf   = (rel >> 6) & 7;
    const int nf   = rel >> 9;
    const int row0 = kf * 32 + (lane >> 4) * 8;
    const int col  = nf * 16 + (lane & 15);

    union { ushort u16[8]; uint4 u4; } ch, cl;
#pragma unroll
    for (int j = 0; j < 8; ++j) {
        float x = W[(size_t)(row0 + j) * N + col];
        ushort h = f2bf_hi(x);
        ch.u16[j] = h;
        cl.u16[j] = f2bf_hi(x - bf2f(h));
    }
    *reinterpret_cast<uint4*>(hi + (size_t)rel * 8) = ch.u4;
    *reinterpret_cast<uint4*>(lo + (size_t)rel * 8) = cl.u4;
}

// ---------------------------------------------------------------------------
// Split-bf16 MFMA GEMM: C = A(MxK,fp32) @ W(KxN) + bias, K=256.
// BM=64, BN=128, BK=32, 256 thr (4 waves), wave tile 16x128 (8 nf frags).
// NPASS=3: acc += Ahi*Bhi + Ahi*Blo + Alo*Bhi ; NPASS=1: Ahi*Bhi only.
// OUT_BF16: store C as bf16 (for value tensor feeding the sampler).
// ---------------------------------------------------------------------------
template<int NPASS, bool OUT_BF16>
__global__ __launch_bounds__(256) void gemm_mfma_kernel(
    const float* __restrict__ A, const ushort* __restrict__ Bhi,
    const ushort* __restrict__ Blo, const float* __restrict__ bias,
    void* __restrict__ Cg, int M, int N, int K)
{
    const int t = threadIdx.x, lane = t & 63, wid = t >> 6;
    const int rowBase = blockIdx.x * 64;
    const int colBase = blockIdx.y * 128;
    const int KF = K >> 5;

    __shared__ ushort Ah[64][40];
    __shared__ ushort Al[64][40];

    f32x4 acc[8];
#pragma unroll
    for (int j = 0; j < 8; ++j) acc[j] = (f32x4)0.0f;

    const int waveRow = wid * 16;
    const int frRow = lane & 15, chunk = lane >> 4;

    for (int kf = 0; kf < KF; ++kf) {
        // ---- stage A tile (64 x 32) fp32 -> bf16 hi/lo ----
#pragma unroll
        for (int i = 0; i < 2; ++i) {
            int idx = i * 256 + t;
            int r = idx >> 3, c4 = (idx & 7) * 4;
            int grow = rowBase + r;
            float4 v = make_float4(0.f, 0.f, 0.f, 0.f);
            if (grow < M)
                v = *reinterpret_cast<const float4*>(A + (size_t)grow * K + kf * 32 + c4);
            ushort h0 = f2bf_hi(v.x), h1 = f2bf_hi(v.y), h2 = f2bf_hi(v.z), h3 = f2bf_hi(v.w);
            *reinterpret_cast<ushort4*>(&Ah[r][c4]) = make_ushort4(h0, h1, h2, h3);
            if (NPASS == 3) {
                ushort l0 = f2bf_hi(v.x - bf2f(h0)), l1 = f2bf_hi(v.y - bf2f(h1));
                ushort l2 = f2bf_hi(v.z - bf2f(h2)), l3 = f2bf_hi(v.w - bf2f(h3));
                *reinterpret_cast<ushort4*>(&Al[r][c4]) = make_ushort4(l0, l1, l2, l3);
            }
        }
        __syncthreads();

        // ---- B fragments from packed global (L2-resident) ----
        uint4 bh[8], bl[8];
#pragma unroll
        for (int f = 0; f < 8; ++f) {
            size_t bidx = ((size_t)((colBase >> 4) + f) * KF + kf) * 64 + lane;
            bh[f] = reinterpret_cast<const uint4*>(Bhi)[bidx];
            if (NPASS == 3) bl[f] = reinterpret_cast<const uint4*>(Blo)[bidx];
        }
        // ---- A fragment from LDS ----
        int row = waveRow + frRow;
        uint4 ahv = *reinterpret_cast<const uint4*>(&Ah[row][chunk * 8]);
        uint4 alv;
        if (NPASS == 3) alv = *reinterpret_cast<const uint4*>(&Al[row][chunk * 8]);

        short8v a = __builtin_bit_cast(short8v, ahv);
#pragma unroll
        for (int f = 0; f < 8; ++f) {
            short8v b = __builtin_bit_cast(short8v, bh[f]);
            acc[f] = __builtin_amdgcn_mfma_f32_16x16x32_bf16(a, b, acc[f], 0, 0, 0);
            if (NPASS == 3) {
                acc[f] = __builtin_amdgcn_mfma_f32_16x16x32_bf16(
                    a, __builtin_bit_cast(short8v, bl[f]), acc[f], 0, 0, 0);
                acc[f] = __builtin_amdgcn_mfma_f32_16x16x32_bf16(
                    __builtin_bit_cast(short8v, alv), b, acc[f], 0, 0, 0);
            }
        }
        __syncthreads();
    }

    // ---- epilogue: bias + store (C/D: col = lane&15, row = (lane>>4)*4+e) ----
    const int colLane = lane & 15, rquad = lane >> 4;
#pragma unroll
    for (int f = 0; f < 8; ++f) {
        int col = colBase + f * 16 + colLane;
        float bv = bias[col];
#pragma unroll
        for (int e = 0; e < 4; ++e) {
            int row = rowBase + waveRow + rquad * 4 + e;
            if (row < M) {
                float r = acc[f][e] + bv;
                if (OUT_BF16)
                    ((ushort*)Cg)[(size_t)row * N + col] = f2bf_hi(r);
                else
                    ((float*)Cg)[(size_t)row * N + col] = r;
            }
        }
    }
}

// ---------------------------------------------------------------------------
// Fused softmax + bilinear sampling on bf16 value.
//   block = 64 threads (1 wave), one (b,q) per block.
//   PREP (x2 batches): point p = t + 64*batch, h=p>>4, lp=p&15; 16-wide shfl
//         softmax; addrs+weights -> LDS [pt][h] stride-9 (conflict-free).
//   MAIN: lane -> h = lane>>3, d4 = (lane&7)*4; bf16x4 (8B) gathers.
// ---------------------------------------------------------------------------
__global__ __launch_bounds__(64) void sampler_kernel(
    const ushort* __restrict__ value,  // (B, LEN_IN, 256) bf16
    const float* __restrict__ offs,    // (B*LQ, 256)
    const float* __restrict__ attnw,   // (B*LQ, 128)
    const float* __restrict__ refp,    // (B, LQ, NL, 2)
    float* __restrict__ mid)           // (B*LQ, 256)
{
    const int bq = blockIdx.x;
    const int t  = threadIdx.x;

    __shared__ float s_ref[NL_ * 2];
    __shared__ int   s_addr[144 * 4];
    __shared__ float s_w[144 * 4];

    if (t < NL_ * 2) s_ref[t] = refp[(size_t)bq * (NL_ * 2) + t];
    __syncthreads();

#pragma unroll
    for (int batch = 0; batch < 2; ++batch) {
        const int p  = t + batch * 64;
        const int h  = p >> 4;
        const int lp = p & 15;
        const int l  = lp >> 2;

        float raw = attnw[(size_t)bq * 128 + p];
        float mx = raw;
#pragma unroll
        for (int m = 8; m >= 1; m >>= 1) mx = fmaxf(mx, __shfl_xor(mx, m, 16));
        float e = __expf(raw - mx);
        float sum = e;
#pragma unroll
        for (int m = 8; m >= 1; m >>= 1) sum += __shfl_xor(sum, m, 16);
        const float aw = e / sum;

        const float2 o = reinterpret_cast<const float2*>(offs)[(size_t)bq * 128 + p];
        const float rx = s_ref[l * 2 + 0];
        const float ry = s_ref[l * 2 + 1];

        const int   Wl = 96 >> l;
        const int   st = 12288 - (12288 >> (2 * l));
        const float fW = (float)Wl;

        const float x = fmaf(rx, fW, o.x) - 0.5f;
        const float y = fmaf(ry, fW, o.y) - 0.5f;
        const float x0f = floorf(x), y0f = floorf(y);
        const float fx = x - x0f, fy = y - y0f;
        const int x0 = (int)x0f, y0 = (int)y0f;
        const int x1 = x0 + 1,   y1 = y0 + 1;

        const float vx0 = (x0 >= 0 && x0 < Wl) ? 1.f : 0.f;
        const float vx1 = (x1 >= 0 && x1 < Wl) ? 1.f : 0.f;
        const float vy0 = (y0 >= 0 && y0 < Wl) ? 1.f : 0.f;
        const float vy1 = (y1 >= 0 && y1 < Wl) ? 1.f : 0.f;

        const int xc0 = min(max(x0, 0), Wl - 1);
        const int xc1 = min(max(x1, 0), Wl - 1);
        const int yc0 = min(max(y0, 0), Wl - 1);
        const int yc1 = min(max(y1, 0), Wl - 1);

        const int row0 = st + yc0 * Wl;
        const int row1 = st + yc1 * Wl;
        const int hb   = h << 5;

        const int sidx = (lp * 9 + h) * 4;
        int4 a;
        a.x = ((row0 + xc0) << 8) + hb;
        a.y = ((row0 + xc1) << 8) + hb;
        a.z = ((row1 + xc0) << 8) + hb;
        a.w = ((row1 + xc1) << 8) + hb;
        *reinterpret_cast<int4*>(&s_addr[sidx]) = a;

        float4 w;
        w.x = aw * (1.f - fx) * (1.f - fy) * vx0 * vy0;
        w.y = aw * fx * (1.f - fy) * vx1 * vy0;
        w.z = aw * (1.f - fx) * fy * vx0 * vy1;
        w.w = aw * fx * fy * vx1 * vy1;
        *reinterpret_cast<float4*>(&s_w[sidx]) = w;
    }
    __syncthreads();

    // ---- MAIN: bf16x4 gathers + weighted sum ----
    const int h  = t >> 3;
    const int d4 = (t & 7) * 4;
    const ushort* __restrict__ vb = value + (bq >= LQ_ ? (size_t)LEN_IN_ * 256 : 0) + d4;

    float a0 = 0.f, a1 = 0.f, a2 = 0.f, a3 = 0.f;
#pragma unroll
    for (int pt = 0; pt < 16; ++pt) {
        const int sidx = (pt * 9 + h) * 4;
        const int4   a = *reinterpret_cast<const int4*>(&s_addr[sidx]);
        const float4 w = *reinterpret_cast<const float4*>(&s_w[sidx]);
        ushort4 v00 = *reinterpret_cast<const ushort4*>(vb + a.x);
        ushort4 v01 = *reinterpret_cast<const ushort4*>(vb + a.y);
        ushort4 v10 = *reinterpret_cast<const ushort4*>(vb + a.z);
        ushort4 v11 = *reinterpret_cast<const ushort4*>(vb + a.w);
        a0 = fmaf(w.x, bf2f(v00.x), a0); a1 = fmaf(w.x, bf2f(v00.y), a1);
        a2 = fmaf(w.x, bf2f(v00.z), a2); a3 = fmaf(w.x, bf2f(v00.w), a3);
        a0 = fmaf(w.y, bf2f(v01.x), a0); a1 = fmaf(w.y, bf2f(v01.y), a1);
        a2 = fmaf(w.y, bf2f(v01.z), a2); a3 = fmaf(w.y, bf2f(v01.w), a3);
        a0 = fmaf(w.z, bf2f(v10.x), a0); a1 = fmaf(w.z, bf2f(v10.y), a1);
        a2 = fmaf(w.z, bf2f(v10.z), a2); a3 = fmaf(w.z, bf2f(v10.w), a3);
        a0 = fmaf(w.w, bf2f(v11.x), a0); a1 = fmaf(w.w, bf2f(v11.y), a1);
        a2 = fmaf(w.w, bf2f(v11.z), a2); a3 = fmaf(w.w, bf2f(v11.w), a3);
    }

    float4 o4; o4.x = a0; o4.y = a1; o4.z = a2; o4.w = a3;
    *reinterpret_cast<float4*>(mid + (size_t)bq * 256 + (h << 5) + d4) = o4;
}

// ---------------------------------------------------------------------------
extern "C" void kernel_launch(void* const* d_in, const int* in_sizes, int n_in,
                              void* d_out, int out_size, void* d_ws, size_t ws_size,
                              hipStream_t stream)
{
    const float* query  = (const float*)d_in[0];
    const float* refp   = (const float*)d_in[1];
    const float* inflat = (const float*)d_in[2];
    const float* W_off  = (const float*)d_in[5];
    const float* b_off  = (const float*)d_in[6];
    const float* W_attn = (const float*)d_in[7];
    const float* b_attn = (const float*)d_in[8];
    const float* W_val  = (const float*)d_in[9];
    const float* b_val  = (const float*)d_in[10];
    const float* W_out  = (const float*)d_in[11];
    const float* b_out  = (const float*)d_in[12];
    float* out = (float*)d_out;

    ushort* value_bf = (ushort*)d_ws;                             // 24480*256 bf16
    float*  offsb = (float*)(value_bf + (size_t)MROWS * C_);      // 24480*256 f32
    float*  attnb = offsb + (size_t)MROWS * C_;                   // 24480*128
    float*  mid   = attnb + (size_t)MROWS * 128;                  // 24480*256
    ushort* pack  = (ushort*)(mid + (size_t)MROWS * C_);

    dim3 blk(256);
    const int GX = (MROWS + 63) / 64;   // 383

    hipLaunchKernelGGL(pack_b_kernel, dim3(112), blk, 0, stream,
                       W_val, W_off, W_attn, W_out, pack);
    hipLaunchKernelGGL((gemm_mfma_kernel<3, true>), dim3(GX, 2), blk, 0, stream,
                       inflat, pack + OFF_VHI, pack + OFF_VLO, b_val, value_bf, MROWS, C_, C_);
    hipLaunchKernelGGL((gemm_mfma_kernel<1, false>), dim3(GX, 2), blk, 0, stream,
                       query, pack + OFF_OHI, pack + OFF_OLO, b_off, offsb, MROWS, C_, C_);
    hipLaunchKernelGGL((gemm_mfma_kernel<1, false>), dim3(GX, 1), blk, 0, stream,
                       query, pack + OFF_AHI, pack + OFF_ALO, b_attn, attnb, MROWS, 128, C_);
    hipLaunchKernelGGL(sampler_kernel, dim3(MROWS), dim3(64), 0, stream,
                       value_bf, offsb, attnb, refp, mid);
    hipLaunchKernelGGL((gemm_mfma_kernel<3, false>), dim3(GX, 2), blk, 0, stream,
                       mid, pack + OFF_UHI, pack + OFF_ULO, b_out, out, MROWS, C_, C_);
}